// Round 18
// baseline (272.698 us; speedup 1.0000x reference)
//
#include <hip/hip_runtime.h>
#include <hip/hip_bf16.h>

// Problem: B=2, S=2048, D=2048, H=16, HD=128
#define B_  2
#define S_  2048
#define D_  2048
#define H_  16
#define HD_ 128

typedef unsigned short u16;
typedef __attribute__((ext_vector_type(8))) short bf16x8;
typedef __attribute__((ext_vector_type(4))) float f32x4;
typedef __attribute__((ext_vector_type(16))) float f32x16;

#define GLOAD_LDS16(g, l)                                                     \
  __builtin_amdgcn_global_load_lds(                                           \
      (const __attribute__((address_space(1))) void*)(g),                     \
      (__attribute__((address_space(3))) void*)(l), 16, 0, 0)

__device__ __forceinline__ u16 f2bf(float f){
  unsigned u; __builtin_memcpy(&u, &f, 4);
  u += 0x7fffu + ((u >> 16) & 1u);     // round-to-nearest-even
  return (u16)(u >> 16);
}
__device__ __forceinline__ float bf2f(u16 h){
  unsigned u = ((unsigned)h) << 16; float f; __builtin_memcpy(&f, &u, 4); return f;
}
__device__ __forceinline__ unsigned pack_bf16x2(float lo, float hi){
  __hip_bfloat162 h2 = __float22bfloat162_rn(float2{lo, hi});  // v_cvt_pk_bf16_f32
  unsigned u; __builtin_memcpy(&u, &h2, 4); return u;
}

// ---------------- cast x (fp32 -> bf16) ----------------
__global__ void cast_x_kernel(const float* __restrict__ x, u16* __restrict__ xb){
  int i = blockIdx.x * 256 + threadIdx.x;            // 2,097,152 float4s
  float4 v = reinterpret_cast<const float4*>(x)[i];
  ushort4 o; o.x = f2bf(v.x); o.y = f2bf(v.y); o.z = f2bf(v.z); o.w = f2bf(v.w);
  reinterpret_cast<ushort4*>(xb)[i] = o;
}

// ---------------- transpose + cast weights: Wt[n][k] = W[k][n] ----------------
__global__ void wtrans_kernel(const float* __restrict__ w0, const float* __restrict__ w1,
                              const float* __restrict__ w2, const float* __restrict__ w3,
                              u16* __restrict__ o0, u16* __restrict__ o1,
                              u16* __restrict__ o2, u16* __restrict__ o3){
  __shared__ float t[32][33];
  const float* src; u16* dst;
  switch (blockIdx.z){
    case 0:  src = w0; dst = o0; break;
    case 1:  src = w1; dst = o1; break;
    case 2:  src = w2; dst = o2; break;
    default: src = w3; dst = o3; break;
  }
  int j0 = blockIdx.x * 32, i0 = blockIdx.y * 32;
  int tx = threadIdx.x & 31, ty = threadIdx.x >> 5;   // 256 thr: 32 x 8
  #pragma unroll
  for (int rr = 0; rr < 4; ++rr)
    t[ty + rr*8][tx] = src[(size_t)(i0 + ty + rr*8) * D_ + j0 + tx];
  __syncthreads();
  #pragma unroll
  for (int rr = 0; rr < 4; ++rr)
    dst[(size_t)(j0 + ty + rr*8) * D_ + i0 + tx] = f2bf(t[tx][ty + rr*8]);
}

// ---------------- 128x128 bf16 GEMM, BK=64, 4 waves, 16x16x32 MFMA ----------------
// R9 configuration exactly (measured: 117 us QKV dispatch, VGPR 84, 0 bank
// conflicts). LDS [128][64] u16 (128B rows) + 16B-slot XOR swizzle slot^=(row&7)
// on BOTH the pre-swizzled global_load_lds source (linear dest) and the ds_read
// side. Grid 2D, m-tile fastest (XCD = m%8 -> A-slice L2-resident).
// RoPE is NOT fused here (R10-R16: every fused epilogue pinned VGPR at 116 ->
// 4 waves/SIMD, QKV 142). Q's rotation moves into attn7's registers; only K
// needs the rope_k memory pass.
// MODE 0: QKV fused over grid.y (48 n-tiles), scatter epilogue. MODE 1: O, fp32.
template<int MODE>
__global__ __launch_bounds__(256) void gemm128_kernel(
    const u16* __restrict__ A,
    const u16* __restrict__ B0, const u16* __restrict__ B1, const u16* __restrict__ B2,
    u16* __restrict__ qb, u16* __restrict__ kb, u16* __restrict__ vtb,
    float* __restrict__ outp)
{
  constexpr int K = 2048;
  __shared__ u16 As[128 * 64];   // 16 KB
  __shared__ u16 Bs[128 * 64];   // 16 KB
  int m0 = blockIdx.x * 128;
  int by = blockIdx.y;
  int which, n0;
  const u16* Bmat;
  if (MODE == 0){ which = by >> 4; n0 = (by & 15) * 128;
                  Bmat = (which == 0) ? B0 : ((which == 1) ? B1 : B2); }
  else          { which = 0; n0 = by * 128; Bmat = B0; }

  int tid  = threadIdx.x;
  int lane = tid & 63;
  int wid  = tid >> 6;
  int wr = wid >> 1, wc = wid & 1;        // 2x2 waves -> 64x64 each
  int g = lane >> 4, r = lane & 15;
  const int sx = r & 7;

  f32x4 zero = {0.f, 0.f, 0.f, 0.f};
  f32x4 acc[4][4];
  #pragma unroll
  for (int i = 0; i < 4; ++i)
    #pragma unroll
    for (int j = 0; j < 4; ++j) acc[i][j] = zero;

  for (int kt = 0; kt < K; kt += 64){
    // stage A,B 128x64 tiles (16 KB each): 1024 chunks, 4 per thread per matrix
    #pragma unroll
    for (int j = 0; j < 4; ++j){
      int cbase = j * 256 + wid * 64;           // wave-uniform LDS chunk base
      int c  = cbase + lane;
      int row = c >> 3, sl = c & 7;
      GLOAD_LDS16(&A[(size_t)(m0 + row) * K + kt + ((sl ^ (row & 7)) * 8)],
                  &As[cbase * 8]);
      GLOAD_LDS16(&Bmat[(size_t)(n0 + row) * K + kt + ((sl ^ (row & 7)) * 8)],
                  &Bs[cbase * 8]);
    }
    asm volatile("s_waitcnt vmcnt(0)" ::: "memory");
    __syncthreads();
    #pragma unroll
    for (int kk = 0; kk < 2; ++kk){
      bf16x8 af[4], bfr[4];
      #pragma unroll
      for (int i = 0; i < 4; ++i)
        af[i]  = *reinterpret_cast<bf16x8*>(
            &As[(wr*64 + i*16 + r) * 64 + (((kk*4 + g) ^ sx) * 8)]);
      #pragma unroll
      for (int i = 0; i < 4; ++i)
        bfr[i] = *reinterpret_cast<bf16x8*>(
            &Bs[(wc*64 + i*16 + r) * 64 + (((kk*4 + g) ^ sx) * 8)]);
      #pragma unroll
      for (int i = 0; i < 4; ++i)
        #pragma unroll
        for (int j = 0; j < 4; ++j)
          acc[i][j] = __builtin_amdgcn_mfma_f32_16x16x32_bf16(af[i], bfr[j], acc[i][j], 0, 0, 0);
    }
    __syncthreads();
  }

  // epilogue; C layout: col = lane&15, row = (lane>>4)*4 + e
  #pragma unroll
  for (int i = 0; i < 4; ++i){
    int row0 = m0 + wr*64 + i*16 + g*4;
    int b  = row0 >> 11, s0 = row0 & (S_ - 1);
    #pragma unroll
    for (int j = 0; j < 4; ++j){
      int col = n0 + wc*64 + j*16 + r;
      if (MODE == 1){
        #pragma unroll
        for (int e = 0; e < 4; ++e)
          outp[(size_t)(row0 + e) * D_ + col] = acc[i][j][e];
      } else {
        int h = col >> 7, d = col & 127;
        int bh = b * H_ + h;
        if (which == 2){
          ushort4 pk;
          pk.x = f2bf(acc[i][j][0]); pk.y = f2bf(acc[i][j][1]);
          pk.z = f2bf(acc[i][j][2]); pk.w = f2bf(acc[i][j][3]);
          *reinterpret_cast<ushort4*>(&vtb[((size_t)bh * HD_ + d) * S_ + s0]) = pk;
        } else {
          u16* dstb = (which == 0) ? qb : kb;
          #pragma unroll
          for (int e = 0; e < 4; ++e)
            dstb[((size_t)bh * S_ + s0 + e) * HD_ + d] = f2bf(acc[i][j][e]);
        }
      }
    }
  }
}

// ---------------- RoPE in place on K only: [bh][s][128] ----------------
// Q's rotation is done in-register inside attn7 (once per Q-fragment load).
__global__ void rope_k_kernel(u16* __restrict__ kbuf){
  int idx = blockIdx.x * 256 + threadIdx.x;   // 32*2048*64 threads
  int j  = idx & 63;
  int s  = (idx >> 6) & (S_ - 1);
  int bh = idx >> 17;
  const float LOG2_1E4 = 13.287712379549449f;
  float inv = exp2f(-(float)(2 * j) * (LOG2_1E4 / 128.f));
  float ang = (float)s * inv;
  float sn = __sinf(ang), cs = __cosf(ang);
  size_t base = ((size_t)bh * S_ + s) * HD_;
  float y1 = bf2f(kbuf[base + j]), y2 = bf2f(kbuf[base + 64 + j]);
  kbuf[base + j]      = f2bf(y1 * cs - y2 * sn);
  kbuf[base + 64 + j] = f2bf(y2 * cs + y1 * sn);
}

// ---------------- attention v7: flash LDS K/V, KVBLK=64, Q-RoPE in registers ----
// Q fragments rotated in-register at load: lane holds Q[qc+r][d=cc*16+hi*8+j];
// pair (d, d+64) = frags (cc, cc+4) at same j -> pure register rotation, 32
// sincos per thread ONCE per block (amortized over the kv loop). K arrives
// pre-rotated from rope_k. exp2-domain softmax; heavy-first qblk map.
__global__ __launch_bounds__(256) void attn7_kernel(
  const u16* __restrict__ qbuf, const u16* __restrict__ kbuf,
  const u16* __restrict__ vtb,  u16* __restrict__ ob)
{
  __shared__ u16 Klds[2][64 * 128];   // 16 KB per buffer
  __shared__ u16 Vlds[2][128 * 64];   // 16 KB per buffer

  const int lane = threadIdx.x & 63;
  const int wid  = threadIdx.x >> 6;     // 0..3 = q-chunk within block
  const int r    = lane & 31;
  const int hi   = lane >> 5;
  const int bh   = blockIdx.x;
  const int qblk = 15 - blockIdx.y;      // heavy blocks dispatched first
  const int qc   = qblk * 128 + wid * 32;
  const int qc32 = qc >> 5;              // diagonal 32-subtile index
  const int T    = 2 * qblk + 2;         // 64-key tiles staged by the block

  const float C1 = 0.12751757f;          // (1/sqrt(128)) * log2(e)
  const float C2 = 1.9218114e-4f;        // (ln2/50)^2

  const size_t sbase = (size_t)bh * S_ * HD_;
  const size_t vbase = (size_t)bh * HD_ * S_;

  // Q fragments: lane holds Q[qc+r][d = cc*16 + hi*8 + j]; apply RoPE in-register
  bf16x8 qf[8];
  {
    const u16* qrow = qbuf + sbase + (size_t)(qc + r) * HD_ + hi * 8;
    #pragma unroll
    for (int cc = 0; cc < 8; ++cc)
      qf[cc] = *reinterpret_cast<const bf16x8*>(qrow + cc * 16);
    const float NEG_L2 = -13.287712379549449f / 64.f;   // -log2(1e4)*2/128
    const float srow = (float)(qc + r);
    #pragma unroll
    for (int cc = 0; cc < 4; ++cc){
      #pragma unroll
      for (int j = 0; j < 8; ++j){
        int d = cc * 16 + hi * 8 + j;
        float inv = exp2f((float)d * NEG_L2);
        float ang = srow * inv;
        float sn = __sinf(ang), cs = __cosf(ang);
        float x1 = bf2f((u16)qf[cc][j]);
        float x2 = bf2f((u16)qf[cc + 4][j]);
        qf[cc][j]     = (short)f2bf(x1 * cs - x2 * sn);
        qf[cc + 4][j] = (short)f2bf(x2 * cs + x1 * sn);
      }
    }
  }

  f32x16 oacc[4];
  #pragma unroll
  for (int i = 0; i < 4; ++i)
    #pragma unroll
    for (int j = 0; j < 16; ++j) oacc[i][j] = 0.f;
  float lsum = 0.f;

  // stage 64-key tile t: K 16KB + V 16KB; 8 gload_lds/thread
  auto stage = [&](int buf, int t){
    const int kv0 = t * 64;
    u16* Kt = &Klds[buf][0];
    u16* Vt = &Vlds[buf][0];
    #pragma unroll
    for (int j = 0; j < 4; ++j){
      const int cbase = j * 256 + wid * 64;   // wave-uniform
      const int ck = cbase + lane;
      const int krow = ck >> 4, kslot = ck & 15;
      GLOAD_LDS16(kbuf + sbase + (size_t)(kv0 + krow) * HD_ + ((kslot ^ (krow & 15)) * 8),
                  Kt + cbase * 8);
      const int vd = ck >> 3, vslot = ck & 7;
      GLOAD_LDS16(vtb + vbase + (size_t)vd * S_ + kv0 + ((vslot ^ (vd & 7)) * 8),
                  Vt + cbase * 8);
    }
  };

  stage(0, 0);
  asm volatile("s_waitcnt vmcnt(0)" ::: "memory");
  __syncthreads();

  for (int t = 0; t < T; ++t){
    const int cur = t & 1;
    if (t + 1 < T) stage(cur ^ 1, t + 1);

    const u16* Kt = &Klds[cur][0];
    const u16* Vt = &Vlds[cur][0];
    #pragma unroll
    for (int sub = 0; sub < 2; ++sub){
      const int t32 = 2 * t + sub;
      if (t32 <= qc32){
        const bool diag = (t32 == qc32);
        // QK^T (swapped): lane holds 16 scores for q col = r
        f32x16 sc;
        #pragma unroll
        for (int j = 0; j < 16; ++j) sc[j] = 0.f;
        #pragma unroll
        for (int cc = 0; cc < 8; ++cc){
          const int row = sub * 32 + r;
          const int slot = (cc * 2 + hi) ^ (r & 15);
          bf16x8 kf = *reinterpret_cast<const bf16x8*>(&Kt[row * 128 + slot * 8]);
          sc = __builtin_amdgcn_mfma_f32_32x32x16_bf16(kf, qf[cc], sc, 0, 0, 0);
        }
        // p = 2^( tt2*(1 - u/3 + 2u^2/15) ), u = tt2^2*C2
        float p[16];
        #pragma unroll
        for (int reg = 0; reg < 16; ++reg){
          float tt2 = sc[reg] * C1;
          float w   = tt2 * tt2 * C2;
          float qp  = fmaf(w, 0.13333333f, -0.33333333f);
          float y2  = fmaf(tt2 * w, qp, tt2);
          float pv  = __builtin_amdgcn_exp2f(y2);
          if (diag){
            int kl = (reg & 3) + 8 * (reg >> 2) + 4 * hi;
            if (kl > r) pv = 0.f;
          }
          p[reg] = pv;
          lsum += pv;
        }
        // pack P to bf16; exchange quads across lane^32 -> PV B-fragments
        unsigned a[4], b[4];
        #pragma unroll
        for (int r4 = 0; r4 < 4; ++r4){
          a[r4] = pack_bf16x2(p[r4*4+0], p[r4*4+1]);
          b[r4] = pack_bf16x2(p[r4*4+2], p[r4*4+3]);
        }
        unsigned ra0 = __shfl_xor(hi ? a[0] : a[1], 32);
        unsigned rb0 = __shfl_xor(hi ? b[0] : b[1], 32);
        unsigned ra1 = __shfl_xor(hi ? a[2] : a[3], 32);
        unsigned rb1 = __shfl_xor(hi ? b[2] : b[3], 32);
        unsigned pw[8];
        pw[0] = hi ? ra0 : a[0];  pw[1] = hi ? rb0 : b[0];
        pw[2] = hi ? a[1] : ra0;  pw[3] = hi ? b[1] : rb0;
        pw[4] = hi ? ra1 : a[2];  pw[5] = hi ? rb1 : b[2];
        pw[6] = hi ? a[3] : ra1;  pw[7] = hi ? b[3] : rb1;
        bf16x8 pb0, pb1;
        __builtin_memcpy(&pb0, &pw[0], 16);
        __builtin_memcpy(&pb1, &pw[4], 16);
        // PV: O^T += V^T . P   (V slots: sub*4+hi, sub*4+2+hi; ^ (d&7))
        #pragma unroll
        for (int i = 0; i < 4; ++i){
          const int d  = i * 32 + r;
          const int sw = d & 7;
          bf16x8 vf0 = *reinterpret_cast<const bf16x8*>(
              &Vt[d * 64 + (((sub * 4 + hi) ^ sw) * 8)]);
          oacc[i] = __builtin_amdgcn_mfma_f32_32x32x16_bf16(vf0, pb0, oacc[i], 0, 0, 0);
          bf16x8 vf1 = *reinterpret_cast<const bf16x8*>(
              &Vt[d * 64 + (((sub * 4 + 2 + hi) ^ sw) * 8)]);
          oacc[i] = __builtin_amdgcn_mfma_f32_32x32x16_bf16(vf1, pb1, oacc[i], 0, 0, 0);
        }
      }
    }
    asm volatile("s_waitcnt vmcnt(0)" ::: "memory");
    __syncthreads();
  }

  float lt = lsum + __shfl_xor(lsum, 32);
  float linv = 1.0f / (1.0f + lt);       // +1 = sink term exp(-m), m=0

  // write: row q = qc+r, dv = i*32 + r4*8 + hi*4 + (0..3)
  const int b = bh >> 4, h = bh & 15;
  u16* orow = ob + ((size_t)(b * S_ + qc + r)) * D_ + h * HD_;
  #pragma unroll
  for (int i = 0; i < 4; ++i){
    #pragma unroll
    for (int r4 = 0; r4 < 4; ++r4){
      ushort4 st;
      st.x = f2bf(oacc[i][r4*4+0] * linv);
      st.y = f2bf(oacc[i][r4*4+1] * linv);
      st.z = f2bf(oacc[i][r4*4+2] * linv);
      st.w = f2bf(oacc[i][r4*4+3] * linv);
      *reinterpret_cast<ushort4*>(orow + i*32 + r4*8 + hi*4) = st;
    }
  }
}

extern "C" void kernel_launch(void* const* d_in, const int* in_sizes, int n_in,
                              void* d_out, int out_size, void* d_ws, size_t ws_size,
                              hipStream_t stream){
  const float* x  = (const float*)d_in[0];
  const float* Wq = (const float*)d_in[1];
  const float* Wk = (const float*)d_in[2];
  const float* Wv = (const float*)d_in[3];
  const float* Wo = (const float*)d_in[4];
  float* out = (float*)d_out;
  char* ws = (char*)d_ws;

  // workspace layout (112 MB total)
  u16* xb   = (u16*)(ws);                      // 16 MB  x bf16 [4096][2048]
  u16* wtq  = (u16*)(ws + (size_t)(16u << 20));//  8 MB  Wq^T bf16 [N][K]
  u16* wtk  = (u16*)(ws + (size_t)(24u << 20));
  u16* wtv  = (u16*)(ws + (size_t)(32u << 20));
  u16* wto  = (u16*)(ws + (size_t)(40u << 20));
  u16* qbuf = (u16*)(ws + (size_t)(48u << 20));// 16 MB  [bh][s][128] (pre-RoPE q)
  u16* kbuf = (u16*)(ws + (size_t)(64u << 20));// 16 MB  [bh][s][128] (rope_k'd)
  u16* vtb  = (u16*)(ws + (size_t)(80u << 20));// 16 MB  [bh][128][s]
  u16* atb  = (u16*)(ws + (size_t)(96u << 20));// 16 MB  [b*S+s][h*128+d]

  cast_x_kernel<<<8192, 256, 0, stream>>>(x, xb);
  wtrans_kernel<<<dim3(64, 64, 4), 256, 0, stream>>>(Wq, Wk, Wv, Wo, wtq, wtk, wtv, wto);
  gemm128_kernel<0><<<dim3(32, 48), 256, 0, stream>>>(xb, wtq, wtk, wtv,
                                                      qbuf, kbuf, vtb, nullptr);
  rope_k_kernel<<<16384, 256, 0, stream>>>(kbuf);
  // grid: bh fastest -> all 16 blocks of a bh land on XCD bh%8
  attn7_kernel<<<dim3(32, 16), 256, 0, stream>>>(qbuf, kbuf, vtb, atb);
  gemm128_kernel<1><<<dim3(32, 16), 256, 0, stream>>>(atb, wto, nullptr, nullptr,
                                                      nullptr, nullptr, nullptr, out);
}

// Round 19
// 267.873 us; speedup vs baseline: 1.0180x; 1.0180x over previous
//
#include <hip/hip_runtime.h>
#include <hip/hip_bf16.h>

// Problem: B=2, S=2048, D=2048, H=16, HD=128
#define B_  2
#define S_  2048
#define D_  2048
#define H_  16
#define HD_ 128

typedef unsigned short u16;
typedef __attribute__((ext_vector_type(8))) short bf16x8;
typedef __attribute__((ext_vector_type(4))) float f32x4;
typedef __attribute__((ext_vector_type(16))) float f32x16;

#define GLOAD_LDS16(g, l)                                                     \
  __builtin_amdgcn_global_load_lds(                                           \
      (const __attribute__((address_space(1))) void*)(g),                     \
      (__attribute__((address_space(3))) void*)(l), 16, 0, 0)

__device__ __forceinline__ u16 f2bf(float f){
  unsigned u; __builtin_memcpy(&u, &f, 4);
  u += 0x7fffu + ((u >> 16) & 1u);     // round-to-nearest-even
  return (u16)(u >> 16);
}
__device__ __forceinline__ float bf2f(u16 h){
  unsigned u = ((unsigned)h) << 16; float f; __builtin_memcpy(&f, &u, 4); return f;
}
__device__ __forceinline__ unsigned pack_bf16x2(float lo, float hi){
  __hip_bfloat162 h2 = __float22bfloat162_rn(float2{lo, hi});  // v_cvt_pk_bf16_f32
  unsigned u; __builtin_memcpy(&u, &h2, 4); return u;
}

// ---------------- cast x (fp32 -> bf16) ----------------
__global__ void cast_x_kernel(const float* __restrict__ x, u16* __restrict__ xb){
  int i = blockIdx.x * 256 + threadIdx.x;            // 2,097,152 float4s
  float4 v = reinterpret_cast<const float4*>(x)[i];
  ushort4 o; o.x = f2bf(v.x); o.y = f2bf(v.y); o.z = f2bf(v.z); o.w = f2bf(v.w);
  reinterpret_cast<ushort4*>(xb)[i] = o;
}

// ---------------- transpose + cast weights: Wt[n][k] = W[k][n] ----------------
__global__ void wtrans_kernel(const float* __restrict__ w0, const float* __restrict__ w1,
                              const float* __restrict__ w2, const float* __restrict__ w3,
                              u16* __restrict__ o0, u16* __restrict__ o1,
                              u16* __restrict__ o2, u16* __restrict__ o3){
  __shared__ float t[32][33];
  const float* src; u16* dst;
  switch (blockIdx.z){
    case 0:  src = w0; dst = o0; break;
    case 1:  src = w1; dst = o1; break;
    case 2:  src = w2; dst = o2; break;
    default: src = w3; dst = o3; break;
  }
  int j0 = blockIdx.x * 32, i0 = blockIdx.y * 32;
  int tx = threadIdx.x & 31, ty = threadIdx.x >> 5;   // 256 thr: 32 x 8
  #pragma unroll
  for (int rr = 0; rr < 4; ++rr)
    t[ty + rr*8][tx] = src[(size_t)(i0 + ty + rr*8) * D_ + j0 + tx];
  __syncthreads();
  #pragma unroll
  for (int rr = 0; rr < 4; ++rr)
    dst[(size_t)(j0 + ty + rr*8) * D_ + i0 + tx] = f2bf(t[tx][ty + rr*8]);
}

// ---------------- 128x128 bf16 GEMM, BK=64, 4 waves, 16x16x32 MFMA ----------------
// LDS [128][64] u16 (128B rows) + 16B-slot XOR swizzle slot^=(row&7) on BOTH the
// pre-swizzled global_load_lds source (linear dest) and the ds_read side
// (R9-measured: 0 bank conflicts). Grid 2D, m-tile fastest (XCD = m%8).
// MODE 0: QKV fused over grid.y (48 n-tiles). q/k epilogue applies RoPE via
// dump-then-rotate with the angle-addition recurrence (best measured TOTAL:
// 268.1 us, R16; unfused/split variants cost more in total, R14/R17).
// NOTE: plain __launch_bounds__(256) — the min-waves form collapses the
// allocator and spills the MAIN LOOP (R13). MODE 1: O-projection, fp32 out.
template<int MODE>
__global__ __launch_bounds__(256) void gemm128_kernel(
    const u16* __restrict__ A,
    const u16* __restrict__ B0, const u16* __restrict__ B1, const u16* __restrict__ B2,
    u16* __restrict__ qb, u16* __restrict__ kb, u16* __restrict__ vtb,
    float* __restrict__ outp)
{
  constexpr int K = 2048;
  __shared__ u16 lds[2][128 * 64];   // [0]=A tile, [1]=B tile; 32 KB total
  u16* As = &lds[0][0];
  u16* Bs = &lds[1][0];
  int m0 = blockIdx.x * 128;
  int by = blockIdx.y;
  int which, n0;
  const u16* Bmat;
  if (MODE == 0){ which = by >> 4; n0 = (by & 15) * 128;
                  Bmat = (which == 0) ? B0 : ((which == 1) ? B1 : B2); }
  else          { which = 0; n0 = by * 128; Bmat = B0; }

  int tid  = threadIdx.x;
  int lane = tid & 63;
  int wid  = tid >> 6;
  int wr = wid >> 1, wc = wid & 1;        // 2x2 waves -> 64x64 each
  int g = lane >> 4, r = lane & 15;
  const int sx = r & 7;

  f32x4 zero = {0.f, 0.f, 0.f, 0.f};
  f32x4 acc[4][4];
  #pragma unroll
  for (int i = 0; i < 4; ++i)
    #pragma unroll
    for (int j = 0; j < 4; ++j) acc[i][j] = zero;

  for (int kt = 0; kt < K; kt += 64){
    // stage A,B 128x64 tiles (16 KB each): 1024 chunks, 4 per thread per matrix
    #pragma unroll
    for (int j = 0; j < 4; ++j){
      int cbase = j * 256 + wid * 64;           // wave-uniform LDS chunk base
      int c  = cbase + lane;
      int row = c >> 3, sl = c & 7;
      GLOAD_LDS16(&A[(size_t)(m0 + row) * K + kt + ((sl ^ (row & 7)) * 8)],
                  &As[cbase * 8]);
      GLOAD_LDS16(&Bmat[(size_t)(n0 + row) * K + kt + ((sl ^ (row & 7)) * 8)],
                  &Bs[cbase * 8]);
    }
    asm volatile("s_waitcnt vmcnt(0)" ::: "memory");
    __syncthreads();
    #pragma unroll
    for (int kk = 0; kk < 2; ++kk){
      bf16x8 af[4], bfr[4];
      #pragma unroll
      for (int i = 0; i < 4; ++i)
        af[i]  = *reinterpret_cast<bf16x8*>(
            &As[(wr*64 + i*16 + r) * 64 + (((kk*4 + g) ^ sx) * 8)]);
      #pragma unroll
      for (int i = 0; i < 4; ++i)
        bfr[i] = *reinterpret_cast<bf16x8*>(
            &Bs[(wc*64 + i*16 + r) * 64 + (((kk*4 + g) ^ sx) * 8)]);
      #pragma unroll
      for (int i = 0; i < 4; ++i)
        #pragma unroll
        for (int j = 0; j < 4; ++j)
          acc[i][j] = __builtin_amdgcn_mfma_f32_16x16x32_bf16(af[i], bfr[j], acc[i][j], 0, 0, 0);
    }
    __syncthreads();
  }

  // ---------------- epilogue; C layout: col = lane&15, row = (lane>>4)*4 + e ----
  if (MODE == 0 && which < 2){
    // ---- q/k with fused RoPE: dump acc (bf16) -> LDS [128][128], then rotate ----
    u16* xch = &lds[0][0];   // 128 rows x 128 cols u16 = 32 KB
    #pragma unroll
    for (int i = 0; i < 4; ++i)
      #pragma unroll
      for (int e = 0; e < 4; ++e){
        int row = wr*64 + i*16 + g*4 + e;
        int sj  = ((row >> 2) & 7) << 3;
        #pragma unroll
        for (int j = 0; j < 4; ++j){
          int col = wc*64 + j*16 + r;
          xch[row * 128 + (col ^ sj)] = f2bf(acc[i][j][e]);
        }
      }
    __syncthreads();
    {
      u16* dstb = (which == 0) ? qb : kb;
      const int h  = n0 >> 7;
      const int b  = m0 >> 11;
      const int bh = b * H_ + h;
      const int d  = tid & 63;             // rotation pair (d, d+64)
      const int wg = tid >> 6;             // wave -> 32-row slab
      const float NEG_L2 = -13.287712379549449f / 64.f;   // -log2(1e4)*2/128
      const float inv = exp2f((float)d * NEG_L2);
      const int s_base = m0 & (S_ - 1);
      // angle-addition recurrence: angles step by `inv` per row; compute
      // sin/cos once for the first row + once for the step, then 4 FMAs/row.
      float ang0 = (float)(s_base + wg * 32) * inv;
      float sn = __sinf(ang0), cs = __cosf(ang0);
      const float sd = __sinf(inv), cd = __cosf(inv);
      for (int k = 0; k < 32; ++k){
        int row = wg * 32 + k;             // wave-uniform
        int s0  = s_base + row;
        int sj = ((row >> 2) & 7) << 3;
        float x1 = bf2f(xch[row * 128 + (d ^ sj)]);
        float x2 = bf2f(xch[row * 128 + 64 + (d ^ sj)]);
        size_t base = ((size_t)bh * S_ + s0) * HD_;
        dstb[base + d]      = f2bf(x1 * cs - x2 * sn);
        dstb[base + 64 + d] = f2bf(x2 * cs + x1 * sn);
        float ns = sn * cd + cs * sd;      // advance angle by `inv`
        float nc = cs * cd - sn * sd;
        sn = ns; cs = nc;
      }
    }
  } else {
    #pragma unroll
    for (int i = 0; i < 4; ++i){
      int row0 = m0 + wr*64 + i*16 + g*4;
      int b  = row0 >> 11, s0 = row0 & (S_ - 1);
      #pragma unroll
      for (int j = 0; j < 4; ++j){
        int col = n0 + wc*64 + j*16 + r;
        if (MODE == 1){
          #pragma unroll
          for (int e = 0; e < 4; ++e)
            outp[(size_t)(row0 + e) * D_ + col] = acc[i][j][e];
        } else {  // which == 2: v, transposed bf16 scatter
          int h = col >> 7, d = col & 127;
          int bh = b * H_ + h;
          ushort4 pk;
          pk.x = f2bf(acc[i][j][0]); pk.y = f2bf(acc[i][j][1]);
          pk.z = f2bf(acc[i][j][2]); pk.w = f2bf(acc[i][j][3]);
          *reinterpret_cast<ushort4*>(&vtb[((size_t)bh * HD_ + d) * S_ + s0]) = pk;
        }
      }
    }
  }
}

// ---------------- attention v6: flash LDS K/V, KVBLK=64, double-buffered ----------
// exp2-domain softmax: p = 2^y, y = tt2*(1 - u/3 + 2u^2/15), tt2 = s*SCALE*log2e,
// u = (s*SCALE/50)^2 = tt2^2*C2. Heavy-first qblk map; no setprio / no pairing.
__global__ __launch_bounds__(256) void attn6_kernel(
  const u16* __restrict__ qbuf, const u16* __restrict__ kbuf,
  const u16* __restrict__ vtb,  u16* __restrict__ ob)
{
  __shared__ u16 Klds[2][64 * 128];   // 16 KB per buffer
  __shared__ u16 Vlds[2][128 * 64];   // 16 KB per buffer

  const int lane = threadIdx.x & 63;
  const int wid  = threadIdx.x >> 6;     // 0..3 = q-chunk within block
  const int r    = lane & 31;
  const int hi   = lane >> 5;
  const int bh   = blockIdx.x;
  const int qblk = 15 - blockIdx.y;      // heavy blocks dispatched first
  const int qc   = qblk * 128 + wid * 32;
  const int qc32 = qc >> 5;              // diagonal 32-subtile index
  const int T    = 2 * qblk + 2;         // 64-key tiles staged by the block

  const float C1 = 0.12751757f;          // (1/sqrt(128)) * log2(e)
  const float C2 = 1.9218114e-4f;        // (ln2/50)^2

  const size_t sbase = (size_t)bh * S_ * HD_;
  const size_t vbase = (size_t)bh * HD_ * S_;

  // Q fragments: lane holds Q[qc+r][d = cc*16 + hi*8 + j]
  bf16x8 qf[8];
  {
    const u16* qrow = qbuf + sbase + (size_t)(qc + r) * HD_ + hi * 8;
    #pragma unroll
    for (int cc = 0; cc < 8; ++cc)
      qf[cc] = *reinterpret_cast<const bf16x8*>(qrow + cc * 16);
  }

  f32x16 oacc[4];
  #pragma unroll
  for (int i = 0; i < 4; ++i)
    #pragma unroll
    for (int j = 0; j < 16; ++j) oacc[i][j] = 0.f;
  float lsum = 0.f;

  // stage 64-key tile t: K 16KB + V 16KB; 8 gload_lds/thread
  auto stage = [&](int buf, int t){
    const int kv0 = t * 64;
    u16* Kt = &Klds[buf][0];
    u16* Vt = &Vlds[buf][0];
    #pragma unroll
    for (int j = 0; j < 4; ++j){
      const int cbase = j * 256 + wid * 64;   // wave-uniform
      const int ck = cbase + lane;
      const int krow = ck >> 4, kslot = ck & 15;
      GLOAD_LDS16(kbuf + sbase + (size_t)(kv0 + krow) * HD_ + ((kslot ^ (krow & 15)) * 8),
                  Kt + cbase * 8);
      const int vd = ck >> 3, vslot = ck & 7;
      GLOAD_LDS16(vtb + vbase + (size_t)vd * S_ + kv0 + ((vslot ^ (vd & 7)) * 8),
                  Vt + cbase * 8);
    }
  };

  stage(0, 0);
  asm volatile("s_waitcnt vmcnt(0)" ::: "memory");
  __syncthreads();

  for (int t = 0; t < T; ++t){
    const int cur = t & 1;
    if (t + 1 < T) stage(cur ^ 1, t + 1);

    const u16* Kt = &Klds[cur][0];
    const u16* Vt = &Vlds[cur][0];
    #pragma unroll
    for (int sub = 0; sub < 2; ++sub){
      const int t32 = 2 * t + sub;
      if (t32 <= qc32){
        const bool diag = (t32 == qc32);
        // QK^T (swapped): lane holds 16 scores for q col = r
        f32x16 sc;
        #pragma unroll
        for (int j = 0; j < 16; ++j) sc[j] = 0.f;
        #pragma unroll
        for (int cc = 0; cc < 8; ++cc){
          const int row = sub * 32 + r;
          const int slot = (cc * 2 + hi) ^ (r & 15);
          bf16x8 kf = *reinterpret_cast<const bf16x8*>(&Kt[row * 128 + slot * 8]);
          sc = __builtin_amdgcn_mfma_f32_32x32x16_bf16(kf, qf[cc], sc, 0, 0, 0);
        }
        // p = 2^( tt2*(1 - u/3 + 2u^2/15) ), u = tt2^2*C2
        float p[16];
        #pragma unroll
        for (int reg = 0; reg < 16; ++reg){
          float tt2 = sc[reg] * C1;
          float w   = tt2 * tt2 * C2;
          float qp  = fmaf(w, 0.13333333f, -0.33333333f);
          float y2  = fmaf(tt2 * w, qp, tt2);
          float pv  = __builtin_amdgcn_exp2f(y2);
          if (diag){
            int kl = (reg & 3) + 8 * (reg >> 2) + 4 * hi;
            if (kl > r) pv = 0.f;
          }
          p[reg] = pv;
          lsum += pv;
        }
        // pack P to bf16; exchange quads across lane^32 -> PV B-fragments
        unsigned a[4], b[4];
        #pragma unroll
        for (int r4 = 0; r4 < 4; ++r4){
          a[r4] = pack_bf16x2(p[r4*4+0], p[r4*4+1]);
          b[r4] = pack_bf16x2(p[r4*4+2], p[r4*4+3]);
        }
        unsigned ra0 = __shfl_xor(hi ? a[0] : a[1], 32);
        unsigned rb0 = __shfl_xor(hi ? b[0] : b[1], 32);
        unsigned ra1 = __shfl_xor(hi ? a[2] : a[3], 32);
        unsigned rb1 = __shfl_xor(hi ? b[2] : b[3], 32);
        unsigned pw[8];
        pw[0] = hi ? ra0 : a[0];  pw[1] = hi ? rb0 : b[0];
        pw[2] = hi ? a[1] : ra0;  pw[3] = hi ? b[1] : rb0;
        pw[4] = hi ? ra1 : a[2];  pw[5] = hi ? rb1 : b[2];
        pw[6] = hi ? a[3] : ra1;  pw[7] = hi ? b[3] : rb1;
        bf16x8 pb0, pb1;
        __builtin_memcpy(&pb0, &pw[0], 16);
        __builtin_memcpy(&pb1, &pw[4], 16);
        // PV: O^T += V^T . P   (V slots: sub*4+hi, sub*4+2+hi; ^ (d&7))
        #pragma unroll
        for (int i = 0; i < 4; ++i){
          const int d  = i * 32 + r;
          const int sw = d & 7;
          bf16x8 vf0 = *reinterpret_cast<const bf16x8*>(
              &Vt[d * 64 + (((sub * 4 + hi) ^ sw) * 8)]);
          oacc[i] = __builtin_amdgcn_mfma_f32_32x32x16_bf16(vf0, pb0, oacc[i], 0, 0, 0);
          bf16x8 vf1 = *reinterpret_cast<const bf16x8*>(
              &Vt[d * 64 + (((sub * 4 + 2 + hi) ^ sw) * 8)]);
          oacc[i] = __builtin_amdgcn_mfma_f32_32x32x16_bf16(vf1, pb1, oacc[i], 0, 0, 0);
        }
      }
    }
    asm volatile("s_waitcnt vmcnt(0)" ::: "memory");
    __syncthreads();
  }

  float lt = lsum + __shfl_xor(lsum, 32);
  float linv = 1.0f / (1.0f + lt);       // +1 = sink term exp(-m), m=0

  // write: row q = qc+r, dv = i*32 + r4*8 + hi*4 + (0..3)
  const int b = bh >> 4, h = bh & 15;
  u16* orow = ob + ((size_t)(b * S_ + qc + r)) * D_ + h * HD_;
  #pragma unroll
  for (int i = 0; i < 4; ++i){
    #pragma unroll
    for (int r4 = 0; r4 < 4; ++r4){
      ushort4 st;
      st.x = f2bf(oacc[i][r4*4+0] * linv);
      st.y = f2bf(oacc[i][r4*4+1] * linv);
      st.z = f2bf(oacc[i][r4*4+2] * linv);
      st.w = f2bf(oacc[i][r4*4+3] * linv);
      *reinterpret_cast<ushort4*>(orow + i*32 + r4*8 + hi*4) = st;
    }
  }
}

extern "C" void kernel_launch(void* const* d_in, const int* in_sizes, int n_in,
                              void* d_out, int out_size, void* d_ws, size_t ws_size,
                              hipStream_t stream){
  const float* x  = (const float*)d_in[0];
  const float* Wq = (const float*)d_in[1];
  const float* Wk = (const float*)d_in[2];
  const float* Wv = (const float*)d_in[3];
  const float* Wo = (const float*)d_in[4];
  float* out = (float*)d_out;
  char* ws = (char*)d_ws;

  // workspace layout (112 MB total)
  u16* xb   = (u16*)(ws);                      // 16 MB  x bf16 [4096][2048]
  u16* wtq  = (u16*)(ws + (size_t)(16u << 20));//  8 MB  Wq^T bf16 [N][K]
  u16* wtk  = (u16*)(ws + (size_t)(24u << 20));
  u16* wtv  = (u16*)(ws + (size_t)(32u << 20));
  u16* wto  = (u16*)(ws + (size_t)(40u << 20));
  u16* qbuf = (u16*)(ws + (size_t)(48u << 20));// 16 MB  [bh][s][128] (post-RoPE)
  u16* kbuf = (u16*)(ws + (size_t)(64u << 20));// 16 MB  [bh][s][128] (post-RoPE)
  u16* vtb  = (u16*)(ws + (size_t)(80u << 20));// 16 MB  [bh][128][s]
  u16* atb  = (u16*)(ws + (size_t)(96u << 20));// 16 MB  [b*S+s][h*128+d]

  cast_x_kernel<<<8192, 256, 0, stream>>>(x, xb);
  wtrans_kernel<<<dim3(64, 64, 4), 256, 0, stream>>>(Wq, Wk, Wv, Wo, wtq, wtk, wtv, wto);
  gemm128_kernel<0><<<dim3(32, 48), 256, 0, stream>>>(xb, wtq, wtk, wtv,
                                                      qbuf, kbuf, vtb, nullptr);
  // grid: bh fastest -> all 16 blocks of a bh land on XCD bh%8
  attn6_kernel<<<dim3(32, 16), 256, 0, stream>>>(qbuf, kbuf, vtb, atb);
  gemm128_kernel<1><<<dim3(32, 16), 256, 0, stream>>>(atb, wto, nullptr, nullptr,
                                                      nullptr, nullptr, nullptr, out);
}